// Round 3
// baseline (132.888 us; speedup 1.0000x reference)
//
#include <hip/hip_runtime.h>
#include <hip/hip_cooperative_groups.h>
#include <math.h>

namespace cg = cooperative_groups;

#define NB 32
#define CC 512
#define HW 1024
#define NJ 10

__device__ __forceinline__ float wave_reduce(float s) {
#pragma unroll
  for (int off = 32; off; off >>= 1) s += __shfl_down(s, off, 64);
  return s;
}

// ============================ one-pass cooperative ============================
// Grid = 512 blocks (n, pblk of 64 p) x 512 threads; 2 blocks/CU co-resident.
// Thread (cg,pg) owns x[cg*16..+15][pg*4..+3] in registers (16 float4, read ONCE).
// A: GAP partials over own 64 p  -> gpart[b][c] (1 MB in d_ws)
//    grid.sync()
// Q: gap[c] = sum_pb gpart -> q = sigmoid(conv5) -> P_j -> invZ  (per block)
// B: s_j[p] = sum_c q_c^j x[c,p]  (j in two halves of 5 to cap VGPRs)
// C: out = x * invZ * sum_j (q_d^j/j!) s_j[p]   (x still in registers)
__global__ __launch_bounds__(512, 4) void k_onepass(
    const float* __restrict__ x, const float* __restrict__ wq,
    const float* __restrict__ bq, float* __restrict__ out,
    float* __restrict__ gpart) {
  int b = blockIdx.x;
  int n = b >> 4;
  int t = threadIdx.x;
  int cg = t >> 4, pg = t & 15;
  int wv = t >> 6, lane = t & 63;

  __shared__ float gs[CC];      // gap staging / gap means
  __shared__ float qs[CC];      // q values
  __shared__ float wred[8][NJ];
  __shared__ float4 sred[8][16][NJ + 1];  // pad -> stride 44 floats, conflict-free
  __shared__ float4 sfin[16][NJ + 1];
  __shared__ float invZ_sh;

  const float cj[NJ] = {1.f, 1.f, 0.5f, 1.f / 6.f, 1.f / 24.f, 1.f / 120.f,
                        1.f / 720.f, 1.f / 5040.f, 1.f / 40320.f, 1.f / 362880.f};

  // ---- load x tile (the only HBM read of x) ----
  float4 xv[16];
  const float4* x4 = (const float4*)x;
  size_t base = (size_t)(n * CC + cg * 16) * 256 + (size_t)(b & 15) * 16 + pg;
#pragma unroll
  for (int i = 0; i < 16; ++i) xv[i] = x4[base + (size_t)i * 256];

  // ---- phase A: GAP partials over this block's 64 p ----
  {
    float ps[16];
#pragma unroll
    for (int i = 0; i < 16; ++i) {
      float4 v = xv[i];
      ps[i] = v.x + v.y + v.z + v.w;
    }
#pragma unroll
    for (int off = 1; off < 16; off <<= 1) {
#pragma unroll
      for (int i = 0; i < 16; ++i) ps[i] += __shfl_xor(ps[i], off, 64);
    }
    if (pg == 0) {  // lanes 0,16,32,48 of each wave
#pragma unroll
      for (int i = 0; i < 16; ++i) gs[cg * 16 + i] = ps[i];
    }
  }
  __syncthreads();
  if (t < 128) ((float4*)&gpart[(size_t)b * CC])[t] = ((const float4*)gs)[t];

  cg::this_grid().sync();

  // ---- phase Q: reduce partials -> gap -> q -> invZ ----
  {
    int c = t;
    float g = 0.f;
#pragma unroll
    for (int pb = 0; pb < 16; ++pb) g += gpart[(size_t)(n * 16 + pb) * CC + c];
    gs[c] = g * (1.0f / 1024.0f);
  }
  __syncthreads();
  {
    int c = t;
    float z = bq[0];
#pragma unroll
    for (int k = 0; k < 5; ++k) {
      int idx = c + k - 2;
      float gv = (idx >= 0 && idx < CC) ? gs[idx] : 0.f;
      z = fmaf(gv, wq[k], z);
    }
    float qv = 1.f / (1.f + expf(-z));
    qs[c] = qv;
    float pj[NJ];
    float pw = 1.f;
#pragma unroll
    for (int j = 0; j < NJ; ++j) { pj[j] = pw; pw *= qv; }
#pragma unroll
    for (int j = 0; j < NJ; ++j) pj[j] = wave_reduce(pj[j]);
    if (lane == 0) {
#pragma unroll
      for (int j = 0; j < NJ; ++j) wred[wv][j] = pj[j];
    }
  }
  __syncthreads();
  if (t == 0) {
    float Z = 0.f;
#pragma unroll
    for (int j = 0; j < NJ; ++j) {
      float P = 0.f;
#pragma unroll
      for (int w8 = 0; w8 < 8; ++w8) P += wred[w8][j];
      Z = fmaf(cj[j] * P, P, Z);
    }
    invZ_sh = 1.f / Z;  // consumed after the sync following phase B
  }

  // ---- phase B: moments, two j-halves (keeps acc at 20 VGPRs) ----
#pragma unroll
  for (int half = 0; half < 2; ++half) {
    float4 acc[5];
#pragma unroll
    for (int j = 0; j < 5; ++j) acc[j] = make_float4(0.f, 0.f, 0.f, 0.f);
#pragma unroll
    for (int i = 0; i < 16; ++i) {
      float qc = qs[cg * 16 + i];
      float4 v = xv[i];
      float w;
      if (half == 0) w = 1.f;
      else { float q2 = qc * qc; w = q2 * q2 * qc; }  // qc^5
#pragma unroll
      for (int j = 0; j < 5; ++j) {
        acc[j].x = fmaf(w, v.x, acc[j].x);
        acc[j].y = fmaf(w, v.y, acc[j].y);
        acc[j].z = fmaf(w, v.z, acc[j].z);
        acc[j].w = fmaf(w, v.w, acc[j].w);
        w *= qc;
      }
    }
#pragma unroll
    for (int j = 0; j < 5; ++j) {
      acc[j].x += __shfl_xor(acc[j].x, 16, 64);
      acc[j].y += __shfl_xor(acc[j].y, 16, 64);
      acc[j].z += __shfl_xor(acc[j].z, 16, 64);
      acc[j].w += __shfl_xor(acc[j].w, 16, 64);
      acc[j].x += __shfl_xor(acc[j].x, 32, 64);
      acc[j].y += __shfl_xor(acc[j].y, 32, 64);
      acc[j].z += __shfl_xor(acc[j].z, 32, 64);
      acc[j].w += __shfl_xor(acc[j].w, 32, 64);
    }
    if (lane < 16) {
#pragma unroll
      for (int j = 0; j < 5; ++j) sred[wv][lane][half * 5 + j] = acc[j];
    }
  }
  __syncthreads();
  if (t < 160) {  // 16 pg x 10 j bins; fold in invZ/j!
    int pp = t / NJ, j = t - pp * NJ;
    float4 a = make_float4(0.f, 0.f, 0.f, 0.f);
#pragma unroll
    for (int w8 = 0; w8 < 8; ++w8) {
      float4 v = sred[w8][pp][j];
      a.x += v.x; a.y += v.y; a.z += v.z; a.w += v.w;
    }
    float sc = cj[j] * invZ_sh;
    a.x *= sc; a.y *= sc; a.z *= sc; a.w *= sc;
    sfin[pp][j] = a;
  }
  __syncthreads();

  // ---- phase C: output from register-held x ----
  float4 sj[NJ];
#pragma unroll
  for (int j = 0; j < NJ; ++j) sj[j] = sfin[pg][j];
  float4* o4 = (float4*)out;
#pragma unroll
  for (int i = 0; i < 16; ++i) {
    float qd = qs[cg * 16 + i];
    float w = 1.f;
    float4 att = make_float4(0.f, 0.f, 0.f, 0.f);
#pragma unroll
    for (int j = 0; j < NJ; ++j) {
      att.x = fmaf(w, sj[j].x, att.x);
      att.y = fmaf(w, sj[j].y, att.y);
      att.z = fmaf(w, sj[j].z, att.z);
      att.w = fmaf(w, sj[j].w, att.w);
      w *= qd;
    }
    float4 xvv = xv[i];
    float4 o;
    o.x = xvv.x * att.x; o.y = xvv.y * att.y;
    o.z = xvv.z * att.z; o.w = xvv.w * att.w;
    o4[base + (size_t)i * 256] = o;
  }
}

// ============================ fallback (R2 path) ============================
__global__ __launch_bounds__(256) void k_gap(const float* __restrict__ x,
                                             float* __restrict__ gap) {
  int wv = threadIdx.x >> 6, lane = threadIdx.x & 63;
  int r0 = blockIdx.x * 16;
#pragma unroll
  for (int it = 0; it < 4; ++it) {
    int row = r0 + wv * 4 + it;
    const float4* xp = (const float4*)x + (size_t)row * 256;
    float s = 0.f;
#pragma unroll
    for (int k = 0; k < 4; ++k) {
      float4 v = xp[lane + 64 * k];
      s += v.x + v.y + v.z + v.w;
    }
    s = wave_reduce(s);
    if (lane == 0) gap[row] = s * (1.0f / 1024.0f);
  }
}

__global__ __launch_bounds__(512) void k_fused(const float* __restrict__ x,
                                               const float* __restrict__ gap,
                                               const float* __restrict__ wq,
                                               const float* __restrict__ bq,
                                               float* __restrict__ out) {
  int n = blockIdx.x >> 4, pblk = blockIdx.x & 15;
  int t = threadIdx.x;
  int cg = t >> 4, pg = t & 15;
  int wv = t >> 6, lane = t & 63;

  __shared__ float qs[CC];
  __shared__ float wred[8][NJ];
  __shared__ float4 sred[8][16][NJ + 1];
  __shared__ float4 sfin[16][NJ + 1];
  __shared__ float invZ_sh;

  const float cj[NJ] = {1.f, 1.f, 0.5f, 1.f / 6.f, 1.f / 24.f, 1.f / 120.f,
                        1.f / 720.f, 1.f / 5040.f, 1.f / 40320.f, 1.f / 362880.f};

  float4 xv[16];
  const float4* x4 = (const float4*)x;
  size_t base = (size_t)(n * CC + cg * 16) * 256 + (size_t)pblk * 16 + pg;
#pragma unroll
  for (int i = 0; i < 16; ++i) xv[i] = x4[base + (size_t)i * 256];

  {
    int c = t;
    const float* g = gap + n * CC;
    float z = bq[0];
#pragma unroll
    for (int k = 0; k < 5; ++k) {
      int idx = c + k - 2;
      float gv = (idx >= 0 && idx < CC) ? g[idx] : 0.f;
      z = fmaf(gv, wq[k], z);
    }
    float qv = 1.f / (1.f + expf(-z));
    qs[c] = qv;
    float pj[NJ];
    float pw = 1.f;
#pragma unroll
    for (int j = 0; j < NJ; ++j) { pj[j] = pw; pw *= qv; }
#pragma unroll
    for (int j = 0; j < NJ; ++j) pj[j] = wave_reduce(pj[j]);
    if (lane == 0) {
#pragma unroll
      for (int j = 0; j < NJ; ++j) wred[wv][j] = pj[j];
    }
  }
  __syncthreads();
  if (t == 0) {
    float Z = 0.f;
#pragma unroll
    for (int j = 0; j < NJ; ++j) {
      float P = 0.f;
#pragma unroll
      for (int w8 = 0; w8 < 8; ++w8) P += wred[w8][j];
      Z = fmaf(cj[j] * P, P, Z);
    }
    invZ_sh = 1.f / Z;
  }

  float4 acc[NJ];
#pragma unroll
  for (int j = 0; j < NJ; ++j) acc[j] = make_float4(0.f, 0.f, 0.f, 0.f);
#pragma unroll
  for (int i = 0; i < 16; ++i) {
    float qc = qs[cg * 16 + i];
    float4 v = xv[i];
    float w = 1.f;
#pragma unroll
    for (int j = 0; j < NJ; ++j) {
      acc[j].x = fmaf(w, v.x, acc[j].x);
      acc[j].y = fmaf(w, v.y, acc[j].y);
      acc[j].z = fmaf(w, v.z, acc[j].z);
      acc[j].w = fmaf(w, v.w, acc[j].w);
      w *= qc;
    }
  }
#pragma unroll
  for (int j = 0; j < NJ; ++j) {
    acc[j].x += __shfl_xor(acc[j].x, 16, 64);
    acc[j].y += __shfl_xor(acc[j].y, 16, 64);
    acc[j].z += __shfl_xor(acc[j].z, 16, 64);
    acc[j].w += __shfl_xor(acc[j].w, 16, 64);
    acc[j].x += __shfl_xor(acc[j].x, 32, 64);
    acc[j].y += __shfl_xor(acc[j].y, 32, 64);
    acc[j].z += __shfl_xor(acc[j].z, 32, 64);
    acc[j].w += __shfl_xor(acc[j].w, 32, 64);
  }
  if (lane < 16) {
#pragma unroll
    for (int j = 0; j < NJ; ++j) sred[wv][lane][j] = acc[j];
  }
  __syncthreads();
  if (t < 160) {
    int pp = t / NJ, j = t - pp * NJ;
    float4 a = make_float4(0.f, 0.f, 0.f, 0.f);
#pragma unroll
    for (int w8 = 0; w8 < 8; ++w8) {
      float4 v = sred[w8][pp][j];
      a.x += v.x; a.y += v.y; a.z += v.z; a.w += v.w;
    }
    float sc = cj[j] * invZ_sh;
    a.x *= sc; a.y *= sc; a.z *= sc; a.w *= sc;
    sfin[pp][j] = a;
  }
  __syncthreads();

  float4 sj[NJ];
#pragma unroll
  for (int j = 0; j < NJ; ++j) sj[j] = sfin[pg][j];
  float4* o4 = (float4*)out;
#pragma unroll
  for (int i = 0; i < 16; ++i) {
    float qd = qs[cg * 16 + i];
    float w = 1.f;
    float4 att = make_float4(0.f, 0.f, 0.f, 0.f);
#pragma unroll
    for (int j = 0; j < NJ; ++j) {
      att.x = fmaf(w, sj[j].x, att.x);
      att.y = fmaf(w, sj[j].y, att.y);
      att.z = fmaf(w, sj[j].z, att.z);
      att.w = fmaf(w, sj[j].w, att.w);
      w *= qd;
    }
    float4 xvv = xv[i];
    float4 o;
    o.x = xvv.x * att.x; o.y = xvv.y * att.y;
    o.z = xvv.z * att.z; o.w = xvv.w * att.w;
    o4[base + (size_t)i * 256] = o;
  }
}

extern "C" void kernel_launch(void* const* d_in, const int* in_sizes, int n_in,
                              void* d_out, int out_size, void* d_ws, size_t ws_size,
                              hipStream_t stream) {
  const float* x  = (const float*)d_in[0];
  const float* wq = (const float*)d_in[1];
  const float* bq = (const float*)d_in[2];
  float* out = (float*)d_out;
  float* gpart = (float*)d_ws;  // 512*512 floats = 1 MB (fully overwritten)

  // Gate the cooperative path on actual occupancy: need 2 blocks/CU so that
  // all 512 blocks are co-resident on 256 CUs.
  int maxB = 0;
  (void)hipOccupancyMaxActiveBlocksPerMultiprocessor(&maxB, (const void*)k_onepass,
                                                     512, 0);
  if (maxB >= 2) {
    void* args[] = {(void*)&x, (void*)&wq, (void*)&bq, (void*)&out, (void*)&gpart};
    hipLaunchCooperativeKernel((const void*)k_onepass, dim3(NB * 16), dim3(512),
                               args, 0, stream);
  } else {
    float* gap = gpart;  // 64 KB
    k_gap<<<NB * CC / 16, 256, 0, stream>>>(x, gap);
    k_fused<<<NB * 16, 512, 0, stream>>>(x, gap, wq, bq, out);
  }
}

// Round 4
// 132.782 us; speedup vs baseline: 1.0008x; 1.0008x over previous
//
#include <hip/hip_runtime.h>
#include <math.h>

#define NB 32
#define CC 512
#define NJ 10

__device__ __forceinline__ float wave_reduce(float s) {
#pragma unroll
  for (int off = 32; off; off >>= 1) s += __shfl_down(s, off, 64);
  return s;
}

// ===================== one-pass, manual grid barrier =====================
// Grid: 256 blocks (n in [0,32) x pb in [0,8)), 512 threads, 1 block/CU.
// Thread (cg,pg): cg=t>>5 owns channels [cg*32, cg*32+32); pg=t&31 owns
// float4 column pb*32+pg. xv[32] = 128 VGPRs, read from HBM exactly once.
//  A: GAP partials (shfl over 32 pg lanes) -> gpart[b][c]
//     inline grid barrier (threadfence release + atomic cnt + acquire spin)
//  Q: gap = sum of 8 partials -> q = sigmoid(conv5) -> P_j -> invZ
//  B: acc_j = sum_i q^j xv[i]; shfl_xor(32) + LDS tree over 8 waves
//     -> sfin[pg][j] = invZ/j! * s_j
//  C: out = xv[i] * sum_j sfin[pg][j] q_d^j   (x never re-read)
__global__ __launch_bounds__(512, 2) void k_onepass(
    const float* __restrict__ x, const float* __restrict__ wq,
    const float* __restrict__ bq, float* __restrict__ out,
    float* __restrict__ gpart, unsigned* __restrict__ cnt) {
  int b = blockIdx.x;
  int n = b >> 3, pb = b & 7;
  int t = threadIdx.x;
  int cg = t >> 5, pg = t & 31;
  int wv = t >> 6, lane = t & 63;

  __shared__ float gs[CC];
  __shared__ float qs[CC];
  __shared__ float wred[8][NJ];
  __shared__ float4 sred[8][32][NJ + 1];  // stride 11 f4: 4-way conflict max, tiny op
  __shared__ float4 sfin[32][NJ + 1];
  __shared__ float invZ_sh;

  const float cj[NJ] = {1.f, 1.f, 0.5f, 1.f / 6.f, 1.f / 24.f, 1.f / 120.f,
                        1.f / 720.f, 1.f / 5040.f, 1.f / 40320.f, 1.f / 362880.f};

  // ---- load x tile (only HBM read of x) ----
  float4 xv[32];
  const float4* x4 = (const float4*)x;
  size_t base = (size_t)(n * CC + cg * 32) * 256 + (size_t)pb * 32 + pg;
#pragma unroll
  for (int i = 0; i < 32; ++i) xv[i] = x4[base + (size_t)i * 256];

  // ---- phase A: GAP partials over this block's 128 p ----
  {
    float ps[32];
#pragma unroll
    for (int i = 0; i < 32; ++i) {
      float4 v = xv[i];
      ps[i] = v.x + v.y + v.z + v.w;
    }
#pragma unroll
    for (int off = 1; off < 32; off <<= 1) {
#pragma unroll
      for (int i = 0; i < 32; ++i) ps[i] += __shfl_xor(ps[i], off, 64);
    }
    if (pg == 0) {  // 16 lanes (one per cg) each write 32 channel partials
      float* gp = gpart + (size_t)b * CC + cg * 32;
#pragma unroll
      for (int i = 0; i < 32; ++i) gp[i] = ps[i];
    }
  }

  // ---- inline grid barrier (256 blocks co-resident via cooperative launch) ----
  __syncthreads();
  if (t == 0) {
    __threadfence();  // release: cross-XCD L2 writeback of gpart
    atomicAdd(cnt, 1u);
    while (__hip_atomic_load(cnt, __ATOMIC_ACQUIRE, __HIP_MEMORY_SCOPE_AGENT) <
           256u) {
      __builtin_amdgcn_s_sleep(2);
    }
  }
  __syncthreads();

  // ---- phase Q: gap -> q -> P_j -> invZ ----
  {
    int c = t;
    float g = 0.f;
#pragma unroll
    for (int k = 0; k < 8; ++k) g += gpart[(size_t)(n * 8 + k) * CC + c];
    gs[c] = g * (1.0f / 1024.0f);
  }
  __syncthreads();
  {
    int c = t;
    float z = bq[0];
#pragma unroll
    for (int k = 0; k < 5; ++k) {
      int idx = c + k - 2;
      float gv = (idx >= 0 && idx < CC) ? gs[idx] : 0.f;
      z = fmaf(gv, wq[k], z);
    }
    float qv = 1.f / (1.f + expf(-z));
    qs[c] = qv;
    float pj[NJ];
    float pw = 1.f;
#pragma unroll
    for (int j = 0; j < NJ; ++j) { pj[j] = pw; pw *= qv; }
#pragma unroll
    for (int j = 0; j < NJ; ++j) pj[j] = wave_reduce(pj[j]);
    if (lane == 0) {
#pragma unroll
      for (int j = 0; j < NJ; ++j) wred[wv][j] = pj[j];
    }
  }
  __syncthreads();  // qs + wred visible
  if (t == 0) {
    float Z = 0.f;
#pragma unroll
    for (int j = 0; j < NJ; ++j) {
      float P = 0.f;
#pragma unroll
      for (int w8 = 0; w8 < 8; ++w8) P += wred[w8][j];
      Z = fmaf(cj[j] * P, P, Z);
    }
    invZ_sh = 1.f / Z;  // consumed after the sync that follows phase B
  }

  // ---- phase B: moments over this thread's 32 channels ----
  float4 acc[NJ];
#pragma unroll
  for (int j = 0; j < NJ; ++j) acc[j] = make_float4(0.f, 0.f, 0.f, 0.f);
#pragma unroll
  for (int i = 0; i < 32; ++i) {
    float qc = qs[cg * 32 + i];
    float4 v = xv[i];
    float w = 1.f;
#pragma unroll
    for (int j = 0; j < NJ; ++j) {
      acc[j].x = fmaf(w, v.x, acc[j].x);
      acc[j].y = fmaf(w, v.y, acc[j].y);
      acc[j].z = fmaf(w, v.z, acc[j].z);
      acc[j].w = fmaf(w, v.w, acc[j].w);
      w *= qc;
    }
  }
  // combine the wave's two channel-groups (lane bit 5)
#pragma unroll
  for (int j = 0; j < NJ; ++j) {
    acc[j].x += __shfl_xor(acc[j].x, 32, 64);
    acc[j].y += __shfl_xor(acc[j].y, 32, 64);
    acc[j].z += __shfl_xor(acc[j].z, 32, 64);
    acc[j].w += __shfl_xor(acc[j].w, 32, 64);
  }
  if (lane < 32) {
#pragma unroll
    for (int j = 0; j < NJ; ++j) sred[wv][lane][j] = acc[j];
  }
  __syncthreads();
  if (t < 320) {  // 32 pg x 10 j bins; fold in invZ/j!
    int pp = t / NJ, j = t - pp * NJ;
    float4 a = make_float4(0.f, 0.f, 0.f, 0.f);
#pragma unroll
    for (int w8 = 0; w8 < 8; ++w8) {
      float4 v = sred[w8][pp][j];
      a.x += v.x; a.y += v.y; a.z += v.z; a.w += v.w;
    }
    float sc = cj[j] * invZ_sh;
    a.x *= sc; a.y *= sc; a.z *= sc; a.w *= sc;
    sfin[pp][j] = a;
  }
  __syncthreads();

  // ---- phase C: output from register-held x ----
  float4 sj[NJ];
#pragma unroll
  for (int j = 0; j < NJ; ++j) sj[j] = sfin[pg][j];
  float4* o4 = (float4*)out;
#pragma unroll
  for (int i = 0; i < 32; ++i) {
    float qd = qs[cg * 32 + i];
    float w = 1.f;
    float4 att = make_float4(0.f, 0.f, 0.f, 0.f);
#pragma unroll
    for (int j = 0; j < NJ; ++j) {
      att.x = fmaf(w, sj[j].x, att.x);
      att.y = fmaf(w, sj[j].y, att.y);
      att.z = fmaf(w, sj[j].z, att.z);
      att.w = fmaf(w, sj[j].w, att.w);
      w *= qd;
    }
    float4 xvv = xv[i];
    float4 o;
    o.x = xvv.x * att.x; o.y = xvv.y * att.y;
    o.z = xvv.z * att.z; o.w = xvv.w * att.w;
    o4[base + (size_t)i * 256] = o;
  }
}

// ===================== fallback (proven R2 path) =====================
__global__ __launch_bounds__(256) void k_gap(const float* __restrict__ x,
                                             float* __restrict__ gap) {
  int wv = threadIdx.x >> 6, lane = threadIdx.x & 63;
  int r0 = blockIdx.x * 16;
#pragma unroll
  for (int it = 0; it < 4; ++it) {
    int row = r0 + wv * 4 + it;
    const float4* xp = (const float4*)x + (size_t)row * 256;
    float s = 0.f;
#pragma unroll
    for (int k = 0; k < 4; ++k) {
      float4 v = xp[lane + 64 * k];
      s += v.x + v.y + v.z + v.w;
    }
    s = wave_reduce(s);
    if (lane == 0) gap[row] = s * (1.0f / 1024.0f);
  }
}

__global__ __launch_bounds__(512) void k_fused(const float* __restrict__ x,
                                               const float* __restrict__ gap,
                                               const float* __restrict__ wq,
                                               const float* __restrict__ bq,
                                               float* __restrict__ out) {
  int n = blockIdx.x >> 4, pblk = blockIdx.x & 15;
  int t = threadIdx.x;
  int cg = t >> 4, pg = t & 15;
  int wv = t >> 6, lane = t & 63;

  __shared__ float qs[CC];
  __shared__ float wred[8][NJ];
  __shared__ float4 sred[8][16][NJ + 1];
  __shared__ float4 sfin[16][NJ + 1];
  __shared__ float invZ_sh;

  const float cj[NJ] = {1.f, 1.f, 0.5f, 1.f / 6.f, 1.f / 24.f, 1.f / 120.f,
                        1.f / 720.f, 1.f / 5040.f, 1.f / 40320.f, 1.f / 362880.f};

  float4 xv[16];
  const float4* x4 = (const float4*)x;
  size_t base = (size_t)(n * CC + cg * 16) * 256 + (size_t)pblk * 16 + pg;
#pragma unroll
  for (int i = 0; i < 16; ++i) xv[i] = x4[base + (size_t)i * 256];

  {
    int c = t;
    const float* g = gap + n * CC;
    float z = bq[0];
#pragma unroll
    for (int k = 0; k < 5; ++k) {
      int idx = c + k - 2;
      float gv = (idx >= 0 && idx < CC) ? g[idx] : 0.f;
      z = fmaf(gv, wq[k], z);
    }
    float qv = 1.f / (1.f + expf(-z));
    qs[c] = qv;
    float pj[NJ];
    float pw = 1.f;
#pragma unroll
    for (int j = 0; j < NJ; ++j) { pj[j] = pw; pw *= qv; }
#pragma unroll
    for (int j = 0; j < NJ; ++j) pj[j] = wave_reduce(pj[j]);
    if (lane == 0) {
#pragma unroll
      for (int j = 0; j < NJ; ++j) wred[wv][j] = pj[j];
    }
  }
  __syncthreads();
  if (t == 0) {
    float Z = 0.f;
#pragma unroll
    for (int j = 0; j < NJ; ++j) {
      float P = 0.f;
#pragma unroll
      for (int w8 = 0; w8 < 8; ++w8) P += wred[w8][j];
      Z = fmaf(cj[j] * P, P, Z);
    }
    invZ_sh = 1.f / Z;
  }

  float4 acc[NJ];
#pragma unroll
  for (int j = 0; j < NJ; ++j) acc[j] = make_float4(0.f, 0.f, 0.f, 0.f);
#pragma unroll
  for (int i = 0; i < 16; ++i) {
    float qc = qs[cg * 16 + i];
    float4 v = xv[i];
    float w = 1.f;
#pragma unroll
    for (int j = 0; j < NJ; ++j) {
      acc[j].x = fmaf(w, v.x, acc[j].x);
      acc[j].y = fmaf(w, v.y, acc[j].y);
      acc[j].z = fmaf(w, v.z, acc[j].z);
      acc[j].w = fmaf(w, v.w, acc[j].w);
      w *= qc;
    }
  }
#pragma unroll
  for (int j = 0; j < NJ; ++j) {
    acc[j].x += __shfl_xor(acc[j].x, 16, 64);
    acc[j].y += __shfl_xor(acc[j].y, 16, 64);
    acc[j].z += __shfl_xor(acc[j].z, 16, 64);
    acc[j].w += __shfl_xor(acc[j].w, 16, 64);
    acc[j].x += __shfl_xor(acc[j].x, 32, 64);
    acc[j].y += __shfl_xor(acc[j].y, 32, 64);
    acc[j].z += __shfl_xor(acc[j].z, 32, 64);
    acc[j].w += __shfl_xor(acc[j].w, 32, 64);
  }
  if (lane < 16) {
#pragma unroll
    for (int j = 0; j < NJ; ++j) sred[wv][lane][j] = acc[j];
  }
  __syncthreads();
  if (t < 160) {
    int pp = t / NJ, j = t - pp * NJ;
    float4 a = make_float4(0.f, 0.f, 0.f, 0.f);
#pragma unroll
    for (int w8 = 0; w8 < 8; ++w8) {
      float4 v = sred[w8][pp][j];
      a.x += v.x; a.y += v.y; a.z += v.z; a.w += v.w;
    }
    float sc = cj[j] * invZ_sh;
    a.x *= sc; a.y *= sc; a.z *= sc; a.w *= sc;
    sfin[pp][j] = a;
  }
  __syncthreads();

  float4 sj[NJ];
#pragma unroll
  for (int j = 0; j < NJ; ++j) sj[j] = sfin[pg][j];
  float4* o4 = (float4*)out;
#pragma unroll
  for (int i = 0; i < 16; ++i) {
    float qd = qs[cg * 16 + i];
    float w = 1.f;
    float4 att = make_float4(0.f, 0.f, 0.f, 0.f);
#pragma unroll
    for (int j = 0; j < NJ; ++j) {
      att.x = fmaf(w, sj[j].x, att.x);
      att.y = fmaf(w, sj[j].y, att.y);
      att.z = fmaf(w, sj[j].z, att.z);
      att.w = fmaf(w, sj[j].w, att.w);
      w *= qd;
    }
    float4 xvv = xv[i];
    float4 o;
    o.x = xvv.x * att.x; o.y = xvv.y * att.y;
    o.z = xvv.z * att.z; o.w = xvv.w * att.w;
    o4[base + (size_t)i * 256] = o;
  }
}

extern "C" void kernel_launch(void* const* d_in, const int* in_sizes, int n_in,
                              void* d_out, int out_size, void* d_ws, size_t ws_size,
                              hipStream_t stream) {
  const float* x  = (const float*)d_in[0];
  const float* wq = (const float*)d_in[1];
  const float* bq = (const float*)d_in[2];
  float* out = (float*)d_out;
  char* ws = (char*)d_ws;

  unsigned* cnt = (unsigned*)ws;          // 4 B barrier counter (zeroed below)
  float* gpart  = (float*)(ws + 256);     // 256 blocks x 512 floats = 512 KB

  int maxB = 0;
  (void)hipOccupancyMaxActiveBlocksPerMultiprocessor(&maxB, (const void*)k_onepass,
                                                     512, 0);
  hipError_t err = hipErrorUnknown;
  if (maxB >= 1) {
    hipMemsetAsync(ws, 0, 256, stream);  // fresh barrier counter every call
    void* args[] = {(void*)&x, (void*)&wq, (void*)&bq, (void*)&out,
                    (void*)&gpart, (void*)&cnt};
    err = hipLaunchCooperativeKernel((const void*)k_onepass, dim3(256), dim3(512),
                                     args, 0, stream);
  }
  if (err != hipSuccess) {
    float* gap = gpart;
    k_gap<<<NB * CC / 16, 256, 0, stream>>>(x, gap);
    k_fused<<<NB * 16, 512, 0, stream>>>(x, gap, wq, bq, out);
  }
}

// Round 5
// 132.266 us; speedup vs baseline: 1.0047x; 1.0039x over previous
//
#include <hip/hip_runtime.h>
#include <math.h>

#define NB 32
#define CC 512
#define NJ 10

__device__ __forceinline__ float wave_reduce(float s) {
#pragma unroll
  for (int off = 32; off; off >>= 1) s += __shfl_down(s, off, 64);
  return s;
}

// ===================== one-pass, manual grid barrier =====================
// Grid: 256 blocks (n, pb in [0,8)), 512 threads, 1 block/CU (co-resident).
// __launch_bounds__(512, 1): empirically arg2 = min BLOCKS/CU on this
// toolchain (R3: arg=4 -> 64 VGPR cap; R4: arg=2 -> 128). arg=1 -> 256 VGPRs,
// enough for xv[32] (128) + acc[5] (20) + sj[10] (40) with NO scratch spill.
__global__ __launch_bounds__(512, 1) void k_onepass(
    const float* __restrict__ x, const float* __restrict__ wq,
    const float* __restrict__ bq, float* __restrict__ out,
    float* __restrict__ gpart, unsigned* __restrict__ cnt) {
  int b = blockIdx.x;
  int n = b >> 3, pb = b & 7;
  int t = threadIdx.x;
  int cg = t >> 5, pg = t & 31;
  int wv = t >> 6, lane = t & 63;

  __shared__ float gs[CC];
  __shared__ float qs[CC];
  __shared__ float wred[8][NJ];
  __shared__ float4 sred[8][32][NJ + 1];
  __shared__ float4 sfin[32][NJ + 1];
  __shared__ float invZ_sh;

  const float cj[NJ] = {1.f, 1.f, 0.5f, 1.f / 6.f, 1.f / 24.f, 1.f / 120.f,
                        1.f / 720.f, 1.f / 5040.f, 1.f / 40320.f, 1.f / 362880.f};

  // ---- load x tile (only HBM read of x) ----
  float4 xv[32];
  const float4* x4 = (const float4*)x;
  size_t base = (size_t)(n * CC + cg * 32) * 256 + (size_t)pb * 32 + pg;
#pragma unroll
  for (int i = 0; i < 32; ++i) xv[i] = x4[base + (size_t)i * 256];

  // ---- phase A: GAP partials over this block's 128 p ----
  {
    float ps[32];
#pragma unroll
    for (int i = 0; i < 32; ++i) {
      float4 v = xv[i];
      ps[i] = v.x + v.y + v.z + v.w;
    }
#pragma unroll
    for (int off = 1; off < 32; off <<= 1) {
#pragma unroll
      for (int i = 0; i < 32; ++i) ps[i] += __shfl_xor(ps[i], off, 64);
    }
    if (pg == 0) {
      float* gp = gpart + (size_t)b * CC + cg * 32;
#pragma unroll
      for (int i = 0; i < 32; ++i) gp[i] = ps[i];
    }
  }

  // ---- inline grid barrier ----
  __syncthreads();
  if (t == 0) {
    __threadfence();  // release: cross-XCD visibility of gpart
    atomicAdd(cnt, 1u);
    while (__hip_atomic_load(cnt, __ATOMIC_ACQUIRE, __HIP_MEMORY_SCOPE_AGENT) <
           256u) {
      __builtin_amdgcn_s_sleep(2);
    }
  }
  __syncthreads();

  // ---- phase Q: gap -> q -> P_j -> invZ ----
  {
    int c = t;
    float g = 0.f;
#pragma unroll
    for (int k = 0; k < 8; ++k) g += gpart[(size_t)(n * 8 + k) * CC + c];
    gs[c] = g * (1.0f / 1024.0f);
  }
  __syncthreads();
  {
    int c = t;
    float z = bq[0];
#pragma unroll
    for (int k = 0; k < 5; ++k) {
      int idx = c + k - 2;
      float gv = (idx >= 0 && idx < CC) ? gs[idx] : 0.f;
      z = fmaf(gv, wq[k], z);
    }
    float qv = 1.f / (1.f + expf(-z));
    qs[c] = qv;
    float pj[NJ];
    float pw = 1.f;
#pragma unroll
    for (int j = 0; j < NJ; ++j) { pj[j] = pw; pw *= qv; }
#pragma unroll
    for (int j = 0; j < NJ; ++j) pj[j] = wave_reduce(pj[j]);
    if (lane == 0) {
#pragma unroll
      for (int j = 0; j < NJ; ++j) wred[wv][j] = pj[j];
    }
  }
  __syncthreads();
  if (t == 0) {
    float Z = 0.f;
#pragma unroll
    for (int j = 0; j < NJ; ++j) {
      float P = 0.f;
#pragma unroll
      for (int w8 = 0; w8 < 8; ++w8) P += wred[w8][j];
      Z = fmaf(cj[j] * P, P, Z);
    }
    invZ_sh = 1.f / Z;  // consumed after the sync following phase B
  }

  // ---- phase B: moments, two j-halves (acc stays at 20 VGPRs) ----
#pragma unroll
  for (int half = 0; half < 2; ++half) {
    float4 acc[5];
#pragma unroll
    for (int j = 0; j < 5; ++j) acc[j] = make_float4(0.f, 0.f, 0.f, 0.f);
#pragma unroll
    for (int i = 0; i < 32; ++i) {
      float qc = qs[cg * 32 + i];
      float4 v = xv[i];
      float w;
      if (half == 0) w = 1.f;
      else { float q2 = qc * qc; w = q2 * q2 * qc; }  // qc^5
#pragma unroll
      for (int j = 0; j < 5; ++j) {
        acc[j].x = fmaf(w, v.x, acc[j].x);
        acc[j].y = fmaf(w, v.y, acc[j].y);
        acc[j].z = fmaf(w, v.z, acc[j].z);
        acc[j].w = fmaf(w, v.w, acc[j].w);
        w *= qc;
      }
    }
    // combine the wave's two channel-groups (lane bit 5)
#pragma unroll
    for (int j = 0; j < 5; ++j) {
      acc[j].x += __shfl_xor(acc[j].x, 32, 64);
      acc[j].y += __shfl_xor(acc[j].y, 32, 64);
      acc[j].z += __shfl_xor(acc[j].z, 32, 64);
      acc[j].w += __shfl_xor(acc[j].w, 32, 64);
    }
    if (lane < 32) {
#pragma unroll
      for (int j = 0; j < 5; ++j) sred[wv][lane][half * 5 + j] = acc[j];
    }
  }
  __syncthreads();
  if (t < 320) {  // 32 pg x 10 j bins; fold in invZ/j!
    int pp = t / NJ, j = t - pp * NJ;
    float4 a = make_float4(0.f, 0.f, 0.f, 0.f);
#pragma unroll
    for (int w8 = 0; w8 < 8; ++w8) {
      float4 v = sred[w8][pp][j];
      a.x += v.x; a.y += v.y; a.z += v.z; a.w += v.w;
    }
    float sc = cj[j] * invZ_sh;
    a.x *= sc; a.y *= sc; a.z *= sc; a.w *= sc;
    sfin[pp][j] = a;
  }
  __syncthreads();

  // ---- phase C: output from register-held x ----
  float4 sj[NJ];
#pragma unroll
  for (int j = 0; j < NJ; ++j) sj[j] = sfin[pg][j];
  float4* o4 = (float4*)out;
#pragma unroll
  for (int i = 0; i < 32; ++i) {
    float qd = qs[cg * 32 + i];
    float w = 1.f;
    float4 att = make_float4(0.f, 0.f, 0.f, 0.f);
#pragma unroll
    for (int j = 0; j < NJ; ++j) {
      att.x = fmaf(w, sj[j].x, att.x);
      att.y = fmaf(w, sj[j].y, att.y);
      att.z = fmaf(w, sj[j].z, att.z);
      att.w = fmaf(w, sj[j].w, att.w);
      w *= qd;
    }
    float4 xvv = xv[i];
    float4 o;
    o.x = xvv.x * att.x; o.y = xvv.y * att.y;
    o.z = xvv.z * att.z; o.w = xvv.w * att.w;
    o4[base + (size_t)i * 256] = o;
  }
}

// ===================== fallback (proven R2 path) =====================
__global__ __launch_bounds__(256) void k_gap(const float* __restrict__ x,
                                             float* __restrict__ gap) {
  int wv = threadIdx.x >> 6, lane = threadIdx.x & 63;
  int r0 = blockIdx.x * 16;
#pragma unroll
  for (int it = 0; it < 4; ++it) {
    int row = r0 + wv * 4 + it;
    const float4* xp = (const float4*)x + (size_t)row * 256;
    float s = 0.f;
#pragma unroll
    for (int k = 0; k < 4; ++k) {
      float4 v = xp[lane + 64 * k];
      s += v.x + v.y + v.z + v.w;
    }
    s = wave_reduce(s);
    if (lane == 0) gap[row] = s * (1.0f / 1024.0f);
  }
}

__global__ __launch_bounds__(512) void k_fused(const float* __restrict__ x,
                                               const float* __restrict__ gap,
                                               const float* __restrict__ wq,
                                               const float* __restrict__ bq,
                                               float* __restrict__ out) {
  int n = blockIdx.x >> 4, pblk = blockIdx.x & 15;
  int t = threadIdx.x;
  int cg = t >> 4, pg = t & 15;
  int wv = t >> 6, lane = t & 63;

  __shared__ float qs[CC];
  __shared__ float wred[8][NJ];
  __shared__ float4 sred[8][16][NJ + 1];
  __shared__ float4 sfin[16][NJ + 1];
  __shared__ float invZ_sh;

  const float cj[NJ] = {1.f, 1.f, 0.5f, 1.f / 6.f, 1.f / 24.f, 1.f / 120.f,
                        1.f / 720.f, 1.f / 5040.f, 1.f / 40320.f, 1.f / 362880.f};

  float4 xv[16];
  const float4* x4 = (const float4*)x;
  size_t base = (size_t)(n * CC + cg * 16) * 256 + (size_t)pblk * 16 + pg;
#pragma unroll
  for (int i = 0; i < 16; ++i) xv[i] = x4[base + (size_t)i * 256];

  {
    int c = t;
    const float* g = gap + n * CC;
    float z = bq[0];
#pragma unroll
    for (int k = 0; k < 5; ++k) {
      int idx = c + k - 2;
      float gv = (idx >= 0 && idx < CC) ? g[idx] : 0.f;
      z = fmaf(gv, wq[k], z);
    }
    float qv = 1.f / (1.f + expf(-z));
    qs[c] = qv;
    float pj[NJ];
    float pw = 1.f;
#pragma unroll
    for (int j = 0; j < NJ; ++j) { pj[j] = pw; pw *= qv; }
#pragma unroll
    for (int j = 0; j < NJ; ++j) pj[j] = wave_reduce(pj[j]);
    if (lane == 0) {
#pragma unroll
      for (int j = 0; j < NJ; ++j) wred[wv][j] = pj[j];
    }
  }
  __syncthreads();
  if (t == 0) {
    float Z = 0.f;
#pragma unroll
    for (int j = 0; j < NJ; ++j) {
      float P = 0.f;
#pragma unroll
      for (int w8 = 0; w8 < 8; ++w8) P += wred[w8][j];
      Z = fmaf(cj[j] * P, P, Z);
    }
    invZ_sh = 1.f / Z;
  }

  float4 acc[NJ];
#pragma unroll
  for (int j = 0; j < NJ; ++j) acc[j] = make_float4(0.f, 0.f, 0.f, 0.f);
#pragma unroll
  for (int i = 0; i < 16; ++i) {
    float qc = qs[cg * 16 + i];
    float4 v = xv[i];
    float w = 1.f;
#pragma unroll
    for (int j = 0; j < NJ; ++j) {
      acc[j].x = fmaf(w, v.x, acc[j].x);
      acc[j].y = fmaf(w, v.y, acc[j].y);
      acc[j].z = fmaf(w, v.z, acc[j].z);
      acc[j].w = fmaf(w, v.w, acc[j].w);
      w *= qc;
    }
  }
#pragma unroll
  for (int j = 0; j < NJ; ++j) {
    acc[j].x += __shfl_xor(acc[j].x, 16, 64);
    acc[j].y += __shfl_xor(acc[j].y, 16, 64);
    acc[j].z += __shfl_xor(acc[j].z, 16, 64);
    acc[j].w += __shfl_xor(acc[j].w, 16, 64);
    acc[j].x += __shfl_xor(acc[j].x, 32, 64);
    acc[j].y += __shfl_xor(acc[j].y, 32, 64);
    acc[j].z += __shfl_xor(acc[j].z, 32, 64);
    acc[j].w += __shfl_xor(acc[j].w, 32, 64);
  }
  if (lane < 16) {
#pragma unroll
    for (int j = 0; j < NJ; ++j) sred[wv][lane][j] = acc[j];
  }
  __syncthreads();
  if (t < 160) {
    int pp = t / NJ, j = t - pp * NJ;
    float4 a = make_float4(0.f, 0.f, 0.f, 0.f);
#pragma unroll
    for (int w8 = 0; w8 < 8; ++w8) {
      float4 v = sred[w8][pp][j];
      a.x += v.x; a.y += v.y; a.z += v.z; a.w += v.w;
    }
    float sc = cj[j] * invZ_sh;
    a.x *= sc; a.y *= sc; a.z *= sc; a.w *= sc;
    sfin[pp][j] = a;
  }
  __syncthreads();

  float4 sj[NJ];
#pragma unroll
  for (int j = 0; j < NJ; ++j) sj[j] = sfin[pg][j];
  float4* o4 = (float4*)out;
#pragma unroll
  for (int i = 0; i < 16; ++i) {
    float qd = qs[cg * 16 + i];
    float w = 1.f;
    float4 att = make_float4(0.f, 0.f, 0.f, 0.f);
#pragma unroll
    for (int j = 0; j < NJ; ++j) {
      att.x = fmaf(w, sj[j].x, att.x);
      att.y = fmaf(w, sj[j].y, att.y);
      att.z = fmaf(w, sj[j].z, att.z);
      att.w = fmaf(w, sj[j].w, att.w);
      w *= qd;
    }
    float4 xvv = xv[i];
    float4 o;
    o.x = xvv.x * att.x; o.y = xvv.y * att.y;
    o.z = xvv.z * att.z; o.w = xvv.w * att.w;
    o4[base + (size_t)i * 256] = o;
  }
}

extern "C" void kernel_launch(void* const* d_in, const int* in_sizes, int n_in,
                              void* d_out, int out_size, void* d_ws, size_t ws_size,
                              hipStream_t stream) {
  const float* x  = (const float*)d_in[0];
  const float* wq = (const float*)d_in[1];
  const float* bq = (const float*)d_in[2];
  float* out = (float*)d_out;
  char* ws = (char*)d_ws;

  unsigned* cnt = (unsigned*)ws;       // barrier counter (zeroed below)
  float* gpart  = (float*)(ws + 256);  // 256 x 512 floats = 512 KB

  int maxB = 0;
  (void)hipOccupancyMaxActiveBlocksPerMultiprocessor(&maxB, (const void*)k_onepass,
                                                     512, 0);
  hipError_t err = hipErrorUnknown;
  if (maxB >= 1) {
    hipMemsetAsync(ws, 0, 256, stream);  // fresh barrier counter every call
    void* args[] = {(void*)&x, (void*)&wq, (void*)&bq, (void*)&out,
                    (void*)&gpart, (void*)&cnt};
    err = hipLaunchCooperativeKernel((const void*)k_onepass, dim3(256), dim3(512),
                                     args, 0, stream);
  }
  if (err != hipSuccess) {
    float* gap = gpart;
    k_gap<<<NB * CC / 16, 256, 0, stream>>>(x, gap);
    k_fused<<<NB * 16, 512, 0, stream>>>(x, gap, wq, bq, out);
  }
}